// Round 4
// baseline (392.182 us; speedup 1.0000x reference)
//
#include <hip/hip_runtime.h>
#include <cstdint>

// VectorQuantizer: x[16,1024,16,16] f32, codebook[1,8192,1024], values[1,8192,1024]
// Round 4: single-barrier ping-pong MFMA dist (latency-hiding prefetch), N-loop
// of 4 chunks per block with in-register running top-2 (butterfly once/block),
// kernel fusion 7->5. Exact fp32 rescore of top-4 preserves argmin parity.

constexpr int Dd = 1024;   // feature dim (GEMM K)
constexpr int Nn = 256;    // tokens per batch
constexpr int Bb = 16;     // batch
constexpr int Kk = 8192;   // codes (GEMM N)
constexpr int Mm = 4096;   // tokens (GEMM M)
constexpr int BM = 128, BN = 128, BK = 32;
constexpr int CPG = 4;                    // chunks (of 128 codes) per block
constexpr int NG = Kk / (CPG * BN);       // 16 n-groups (grid.x)
constexpr int ITERS = CPG * (Dd / BK);    // 128 pipelined stages
constexpr int NCAND = NG * 2;             // 32 candidates per token

typedef __attribute__((ext_vector_type(8))) short bffrag;   // 8 bf16 = 4 VGPRs
typedef __attribute__((ext_vector_type(4))) float f32x4;
typedef unsigned long long u64;

__device__ __forceinline__ ushort f2bf(float f) {  // fp32 -> bf16 RNE
    uint32_t u = __float_as_uint(f);
    return (ushort)((u + 0x7FFFu + ((u >> 16) & 1u)) >> 16);
}

__device__ __forceinline__ void gload16(const void* g, void* l) {
    __builtin_amdgcn_global_load_lds((const __attribute__((address_space(1))) uint32_t*)g,
                                     (__attribute__((address_space(3))) uint32_t*)l, 16, 0, 0);
}

__device__ __forceinline__ void mm2(u64& a, u64& b) {  // sort pair ascending
    u64 lo = a < b ? a : b;
    u64 hi = a < b ? b : a;
    a = lo; b = hi;
}
// merge sorted pairs: (a1,a2) <- top-2 of {a1,a2,b1,b2}
__device__ __forceinline__ void merge2(u64& a1, u64& a2, u64 b1, u64 b2) {
    u64 t1 = a1 < b1 ? a1 : b1;
    u64 hi = a1 < b1 ? b1 : a1;
    u64 l2 = a2 < b2 ? a2 : b2;
    a2 = hi < l2 ? hi : l2;
    a1 = t1;
}

// ---------- prep: (a) cb -> bf16 + exact ||e||^2, (b) x -> bf16 A (transposed) ----------
// grid 8192 + 512 blocks, 256 threads.
__global__ __launch_bounds__(256) void prep_kernel(const float* __restrict__ x,
                                                   const float* __restrict__ cb,
                                                   ushort* __restrict__ A,
                                                   ushort* __restrict__ Bm,
                                                   float* __restrict__ esq) {
    const int tid = threadIdx.x;
    if (blockIdx.x < (unsigned)Kk) {  // codebook part
        __shared__ float red[4];
        const int k = blockIdx.x;
        float4 v = *(const float4*)&cb[(size_t)k * Dd + tid * 4];
        ushort4 o;
        o.x = f2bf(v.x); o.y = f2bf(v.y); o.z = f2bf(v.z); o.w = f2bf(v.w);
        *(ushort4*)&Bm[(size_t)k * Dd + tid * 4] = o;
        float ss = v.x * v.x + v.y * v.y + v.z * v.z + v.w * v.w;
#pragma unroll
        for (int off = 32; off; off >>= 1) ss += __shfl_down(ss, off, 64);
        if ((tid & 63) == 0) red[tid >> 6] = ss;
        __syncthreads();
        if (tid == 0) esq[k] = red[0] + red[1] + red[2] + red[3];
    } else {  // x part: transpose + bf16
        const int bb = blockIdx.x - Kk;
        const int b = bb >> 5, d0 = (bb & 31) * 32, n = tid;
        const float* xb = x + (size_t)b * Dd * Nn + n;
        ushort* arow = A + (size_t)(b * Nn + n) * Dd + d0;
#pragma unroll
        for (int jj = 0; jj < 4; ++jj) {
            ushort tmp[8];
#pragma unroll
            for (int j = 0; j < 8; ++j) tmp[j] = f2bf(xb[(size_t)(d0 + jj * 8 + j) * Nn]);
            *(uint4*)&arow[jj * 8] = *(const uint4*)tmp;
        }
    }
}

// ---------- x -> xT fp32 [4096][1024] (AFTER dist; aliases Abf/Bbf region) ----------
__global__ __launch_bounds__(256) void transx_kernel(const float* __restrict__ x,
                                                     float* __restrict__ xT) {
    const int n = threadIdx.x, b = blockIdx.x, d0 = blockIdx.y * 32;
    const float* xb = x + (size_t)b * Dd * Nn + n;
    float* row = xT + (size_t)(b * Nn + n) * Dd + d0;
#pragma unroll
    for (int jj = 0; jj < 8; ++jj) {
        float4 v;
        v.x = xb[(size_t)(d0 + jj * 4 + 0) * Nn];
        v.y = xb[(size_t)(d0 + jj * 4 + 1) * Nn];
        v.z = xb[(size_t)(d0 + jj * 4 + 2) * Nn];
        v.w = xb[(size_t)(d0 + jj * 4 + 3) * Nn];
        *(float4*)&row[jj * 4] = v;
    }
}

// ---------- MFMA distance, ping-pong single-barrier, 4 chunks/block ----------
// grid (NG=16, Mm/BM=32); 4 waves; wave w owns rows w*32..w*32+31 x 128 cols.
__global__ __launch_bounds__(256) void mfma_dist_kernel(const ushort* __restrict__ A,
                                                        const ushort* __restrict__ Bm,
                                                        const float* __restrict__ esq,
                                                        u64* __restrict__ cand) {
    __shared__ ushort As[2][4096];  // 8 KB per buffer
    __shared__ ushort Bs[2][4096];

    const int tid = threadIdx.x, lane = tid & 63, w = tid >> 6;
    const int mBase = blockIdx.y * BM;
    const int nGroup = blockIdx.x;
    const int nBase0 = nGroup * (CPG * BN);

    f32x4 acc[2][8];
#pragma unroll
    for (int i = 0; i < 2; ++i)
#pragma unroll
        for (int j = 0; j < 8; ++j) acc[i][j] = (f32x4)0.f;
    u64 r1[8], r2[8];
#pragma unroll
    for (int s = 0; s < 8; ++s) { r1[s] = ~0ULL; r2[s] = ~0ULL; }

    // staging bases: wave w stages row-groups 2w, 2w+1 of A and B
    const int g = 2 * w, r = lane & 15, q = lane >> 4;
    const ushort* aB0 = A + (size_t)(mBase + (g + 0) * 16 + r) * Dd + q * 8;
    const ushort* aB1 = A + (size_t)(mBase + (g + 1) * 16 + r) * Dd + q * 8;
    const ushort* bB0 = Bm + (size_t)(nBase0 + (g + 0) * 16 + r) * Dd + q * 8;
    const ushort* bB1 = Bm + (size_t)(nBase0 + (g + 1) * 16 + r) * Dd + q * 8;

    // stage(it): loads for iteration `it` into buffer it&1 (no waits here)
    auto stage = [&](int it) {
        const int buf = it & 1;
        const int dk = (it & 31) * BK;
        const size_t bOff = (size_t)(it >> 5) * (BN * Dd) + dk;
        gload16(aB0 + dk, &As[buf][(g + 0) * 512]);
        gload16(aB1 + dk, &As[buf][(g + 1) * 512]);
        gload16(bB0 + bOff, &Bs[buf][(g + 0) * 512]);
        gload16(bB1 + bOff, &Bs[buf][(g + 1) * 512]);
    };

    stage(0);
    for (int c = 0; c < CPG; ++c) {
        for (int kk = 0; kk < Dd / BK; ++kk) {
            const int it = c * (Dd / BK) + kk;
            __syncthreads();  // drains vmcnt: stage(it) complete; prev buf reads done
            if (it + 1 < ITERS) stage(it + 1);
            const int buf = it & 1;
            bffrag af[2], bfr[8];
#pragma unroll
            for (int mi = 0; mi < 2; ++mi)
                af[mi] = *(const bffrag*)&As[buf][((2 * w + mi) * 64 + lane) * 8];
#pragma unroll
            for (int ni = 0; ni < 8; ++ni)
                bfr[ni] = *(const bffrag*)&Bs[buf][(ni * 64 + lane) * 8];
#pragma unroll
            for (int mi = 0; mi < 2; ++mi)
#pragma unroll
                for (int ni = 0; ni < 8; ++ni)
                    acc[mi][ni] = __builtin_amdgcn_mfma_f32_16x16x32_bf16(
                        af[mi], bfr[ni], acc[mi][ni], 0, 0, 0);
        }
        // chunk merge: per-lane running top-2 (no cross-lane traffic)
        const int colBase = nBase0 + c * BN;
        uint32_t colc[8];
        float e8[8];
#pragma unroll
        for (int ni = 0; ni < 8; ++ni) {
            colc[ni] = (uint32_t)(colBase + ni * 16 + (lane & 15));
            e8[ni] = esq[colc[ni]];
        }
#pragma unroll
        for (int mi = 0; mi < 2; ++mi) {
#pragma unroll
            for (int reg = 0; reg < 4; ++reg) {
                const int seq = mi * 4 + reg;
                u64 p[8];
#pragma unroll
                for (int ni = 0; ni < 8; ++ni) {
                    float s = fmaxf(fmaf(-2.f, acc[mi][ni][reg], e8[ni]), 0.f);
                    p[ni] = ((u64)__float_as_uint(s) << 32) | colc[ni];
                }
                mm2(p[0], p[1]); mm2(p[2], p[3]); mm2(p[4], p[5]); mm2(p[6], p[7]);
                merge2(p[0], p[1], p[2], p[3]);
                merge2(p[4], p[5], p[6], p[7]);
                merge2(p[0], p[1], p[4], p[5]);
                merge2(r1[seq], r2[seq], p[0], p[1]);
            }
        }
#pragma unroll
        for (int i = 0; i < 2; ++i)
#pragma unroll
            for (int j = 0; j < 8; ++j) acc[i][j] = (f32x4)0.f;
    }

    // final: butterfly across the 16 col-lanes, once per block
#pragma unroll
    for (int mi = 0; mi < 2; ++mi) {
#pragma unroll
        for (int reg = 0; reg < 4; ++reg) {
            const int seq = mi * 4 + reg;
            u64 t1 = r1[seq], t2 = r2[seq];
#pragma unroll
            for (int d = 1; d < 16; d <<= 1) {
                u64 o1 = __shfl_xor(t1, d, 64);
                u64 o2 = __shfl_xor(t2, d, 64);
                merge2(t1, t2, o1, o2);
            }
            if ((lane & 15) == 0) {
                const int t = mBase + w * 32 + mi * 16 + (lane >> 4) * 4 + reg;
                cand[(size_t)t * NCAND + nGroup * 2 + 0] = t1;
                cand[(size_t)t * NCAND + nGroup * 2 + 1] = t2;
            }
        }
    }
}

// ---------- fused select(top-4 of 32) + exact fp32 rescore ----------
// grid 4096 (one block per token), 256 threads.
__global__ __launch_bounds__(256) void selres_kernel(const u64* __restrict__ cand,
                                                     const float* __restrict__ xT,
                                                     const float* __restrict__ cb,
                                                     const float* __restrict__ esq,
                                                     int* __restrict__ fidx) {
    __shared__ int cs[4];
    __shared__ float red[4][4];
    const int t = blockIdx.x, tid = threadIdx.x;
    if (tid < 64) {  // wave 0: global top-4 of the 32 candidates
        u64 v = (tid < NCAND) ? cand[(size_t)t * NCAND + tid] : ~0ULL;
#pragma unroll
        for (int rd = 0; rd < 4; ++rd) {
            u64 m = v;
#pragma unroll
            for (int d = 32; d; d >>= 1) {
                u64 o = __shfl_xor(m, d, 64);
                m = m < o ? m : o;
            }
            if (tid == 0) cs[rd] = (int)(uint32_t)m;
            if (v == m) v = ~0ULL;  // packed keys unique per token
        }
    }
    __syncthreads();
    int c[4];
#pragma unroll
    for (int j = 0; j < 4; ++j) c[j] = cs[j];
    float4 xv = *(const float4*)&xT[(size_t)t * Dd + tid * 4];
    float part[4];
#pragma unroll
    for (int cc = 0; cc < 4; ++cc) {
        float4 wv = *(const float4*)&cb[(size_t)c[cc] * Dd + tid * 4];
        part[cc] = xv.x * wv.x + xv.y * wv.y + xv.z * wv.z + xv.w * wv.w;
    }
#pragma unroll
    for (int cc = 0; cc < 4; ++cc)
#pragma unroll
        for (int off = 32; off; off >>= 1) part[cc] += __shfl_down(part[cc], off, 64);
    if ((tid & 63) == 0)
#pragma unroll
        for (int cc = 0; cc < 4; ++cc) red[tid >> 6][cc] = part[cc];
    __syncthreads();
    if (tid == 0) {
        float bs = 1e30f;
        int bi = 0x7FFFFFFF;
#pragma unroll
        for (int cc = 0; cc < 4; ++cc) {
            float cross = red[0][cc] + red[1][cc] + red[2][cc] + red[3][cc];
            float s = fmaf(-2.f, cross, esq[c[cc]]);
            if (s < bs || (s == bs && c[cc] < bi)) { bs = s; bi = c[cc]; }
        }
        fidx[t] = bi;
    }
}

// ---------- gather values -> out ----------
__global__ __launch_bounds__(256) void gather_kernel(const int* __restrict__ fidx,
                                                     const float* __restrict__ values,
                                                     float* __restrict__ out) {
    const int n = threadIdx.x, b = blockIdx.x, dc = blockIdx.y;
    const int row = fidx[b * Nn + n];
    const float* src = values + (size_t)row * Dd + dc * 64;
    float* dst = out + (size_t)b * Dd * Nn + (size_t)dc * 64 * Nn + n;
#pragma unroll
    for (int j = 0; j < 64; j += 4) {
        float4 v = *(const float4*)(src + j);
        dst[(j + 0) * Nn] = v.x;
        dst[(j + 1) * Nn] = v.y;
        dst[(j + 2) * Nn] = v.z;
        dst[(j + 3) * Nn] = v.w;
    }
}

extern "C" void kernel_launch(void* const* d_in, const int* in_sizes, int n_in,
                              void* d_out, int out_size, void* d_ws, size_t ws_size,
                              hipStream_t stream) {
    const float* x = (const float*)d_in[0];
    const float* cb = (const float*)d_in[1];
    const float* vals = (const float*)d_in[2];
    float* out = (float*)d_out;

    // ws layout (~25.1 MB). xT (16 MB) aliases Abf+Bbf (dead after dist).
    char* p = (char*)d_ws;
    ushort* Abf = (ushort*)p;                 p += (size_t)Mm * Dd * 2;        // 8 MB
    ushort* Bbf = (ushort*)p;                 p += (size_t)Kk * Dd * 2;        // 16 MB
    float* esq = (float*)p;                   p += (size_t)Kk * 4;             // 32 KB
    u64* cand = (u64*)p;                      p += (size_t)Mm * NCAND * 8;     // 1 MB
    int* fidx = (int*)p;                                                       // 16 KB
    float* xT = (float*)d_ws;  // [4096][1024] fp32, reuses first 16 MB

    prep_kernel<<<Kk + 512, 256, 0, stream>>>(x, cb, Abf, Bbf, esq);
    mfma_dist_kernel<<<dim3(NG, Mm / BM), 256, 0, stream>>>(Abf, Bbf, esq, cand);
    transx_kernel<<<dim3(Bb, 32), 256, 0, stream>>>(x, xT);
    selres_kernel<<<Mm, 256, 0, stream>>>(cand, xT, cb, esq, fidx);
    gather_kernel<<<dim3(Bb, Dd / 64), 256, 0, stream>>>(fidx, vals, out);
}

// Round 5
// 282.132 us; speedup vs baseline: 1.3901x; 1.3901x over previous
//
#include <hip/hip_runtime.h>
#include <cstdint>

// VectorQuantizer: x[16,1024,16,16] f32, codebook[1,8192,1024], values[1,8192,1024]
// Round 5: back to r3's 2048-block high-occupancy dist shape (BM=BN=128, 4 waves,
// one 128-code chunk per block) + ping-pong double-buffer prefetch (single
// barrier/iter) + XCD-aware block swizzle for L2 locality. Tail kept from r4.

constexpr int Dd = 1024;   // feature dim (GEMM K)
constexpr int Nn = 256;    // tokens per batch
constexpr int Bb = 16;     // batch
constexpr int Kk = 8192;   // codes (GEMM N)
constexpr int Mm = 4096;   // tokens (GEMM M)
constexpr int BM = 128, BN = 128, BK = 32;
constexpr int NCHUNK = Kk / BN;     // 64 chunks of 128 codes
constexpr int NCAND = NCHUNK * 2;   // 128 candidates per token
constexpr int KITERS = Dd / BK;     // 32

typedef __attribute__((ext_vector_type(8))) short bffrag;   // 8 bf16 = 4 VGPRs
typedef __attribute__((ext_vector_type(4))) float f32x4;
typedef unsigned long long u64;

__device__ __forceinline__ ushort f2bf(float f) {  // fp32 -> bf16 RNE
    uint32_t u = __float_as_uint(f);
    return (ushort)((u + 0x7FFFu + ((u >> 16) & 1u)) >> 16);
}

__device__ __forceinline__ void gload16(const void* g, void* l) {
    __builtin_amdgcn_global_load_lds((const __attribute__((address_space(1))) uint32_t*)g,
                                     (__attribute__((address_space(3))) uint32_t*)l, 16, 0, 0);
}

__device__ __forceinline__ void mm2(u64& a, u64& b) {  // sort pair ascending
    u64 lo = a < b ? a : b;
    u64 hi = a < b ? b : a;
    a = lo; b = hi;
}
// merge sorted pairs: (a1,a2) <- top-2 of {a1,a2,b1,b2}
__device__ __forceinline__ void merge2(u64& a1, u64& a2, u64 b1, u64 b2) {
    u64 t1 = a1 < b1 ? a1 : b1;
    u64 hi = a1 < b1 ? b1 : a1;
    u64 l2 = a2 < b2 ? a2 : b2;
    a2 = hi < l2 ? hi : l2;
    a1 = t1;
}

// ---------- prep: (a) cb -> bf16 + exact ||e||^2, (b) x -> bf16 A (transposed) ----------
__global__ __launch_bounds__(256) void prep_kernel(const float* __restrict__ x,
                                                   const float* __restrict__ cb,
                                                   ushort* __restrict__ A,
                                                   ushort* __restrict__ Bm,
                                                   float* __restrict__ esq) {
    const int tid = threadIdx.x;
    if (blockIdx.x < (unsigned)Kk) {  // codebook part
        __shared__ float red[4];
        const int k = blockIdx.x;
        float4 v = *(const float4*)&cb[(size_t)k * Dd + tid * 4];
        ushort4 o;
        o.x = f2bf(v.x); o.y = f2bf(v.y); o.z = f2bf(v.z); o.w = f2bf(v.w);
        *(ushort4*)&Bm[(size_t)k * Dd + tid * 4] = o;
        float ss = v.x * v.x + v.y * v.y + v.z * v.z + v.w * v.w;
#pragma unroll
        for (int off = 32; off; off >>= 1) ss += __shfl_down(ss, off, 64);
        if ((tid & 63) == 0) red[tid >> 6] = ss;
        __syncthreads();
        if (tid == 0) esq[k] = red[0] + red[1] + red[2] + red[3];
    } else {  // x part: transpose + bf16
        const int bb = blockIdx.x - Kk;
        const int b = bb >> 5, d0 = (bb & 31) * 32, n = tid;
        const float* xb = x + (size_t)b * Dd * Nn + n;
        ushort* arow = A + (size_t)(b * Nn + n) * Dd + d0;
#pragma unroll
        for (int jj = 0; jj < 4; ++jj) {
            ushort tmp[8];
#pragma unroll
            for (int j = 0; j < 8; ++j) tmp[j] = f2bf(xb[(size_t)(d0 + jj * 8 + j) * Nn]);
            *(uint4*)&arow[jj * 8] = *(const uint4*)tmp;
        }
    }
}

// ---------- x -> xT fp32 [4096][1024] (AFTER dist; aliases Abf/Bbf region) ----------
__global__ __launch_bounds__(256) void transx_kernel(const float* __restrict__ x,
                                                     float* __restrict__ xT) {
    const int n = threadIdx.x, b = blockIdx.x, d0 = blockIdx.y * 32;
    const float* xb = x + (size_t)b * Dd * Nn + n;
    float* row = xT + (size_t)(b * Nn + n) * Dd + d0;
#pragma unroll
    for (int jj = 0; jj < 8; ++jj) {
        float4 v;
        v.x = xb[(size_t)(d0 + jj * 4 + 0) * Nn];
        v.y = xb[(size_t)(d0 + jj * 4 + 1) * Nn];
        v.z = xb[(size_t)(d0 + jj * 4 + 2) * Nn];
        v.w = xb[(size_t)(d0 + jj * 4 + 3) * Nn];
        *(float4*)&row[jj * 4] = v;
    }
}

// ---------- MFMA distance, ping-pong prefetch, XCD swizzle ----------
// grid (64, 32) = 2048 blocks; 4 waves; wave w owns rows w*32..+31 x 128 cols.
__global__ __launch_bounds__(256) void mfma_dist_kernel(const ushort* __restrict__ A,
                                                        const ushort* __restrict__ Bm,
                                                        const float* __restrict__ esq,
                                                        u64* __restrict__ cand) {
    __shared__ ushort As[2][4096];  // 8 KB per buffer
    __shared__ ushort Bs[2][4096];

    const int tid = threadIdx.x, lane = tid & 63, w = tid >> 6;
    // XCD swizzle: each XCD owns 4 m-tiles (1 MB of A stays L2-resident),
    // B-tiles get 4-way reuse within an XCD's L2.
    const int id = blockIdx.y * 64 + blockIdx.x;
    const int xcd = id & 7, local = id >> 3;
    const int mG = (xcd << 2) | (local & 3);  // [0,32)
    const int nG = local >> 2;                // [0,64)
    const int mBase = mG * BM, nBase = nG * BN;

    f32x4 acc[2][8];
#pragma unroll
    for (int i = 0; i < 2; ++i)
#pragma unroll
        for (int j = 0; j < 8; ++j) acc[i][j] = (f32x4)0.f;

    // staging: wave w stages row-groups 2w, 2w+1 of A and B
    const int g = 2 * w, r = lane & 15, q = lane >> 4;
    const ushort* aS0 = A + (size_t)(mBase + (g + 0) * 16 + r) * Dd + q * 8;
    const ushort* aS1 = A + (size_t)(mBase + (g + 1) * 16 + r) * Dd + q * 8;
    const ushort* bS0 = Bm + (size_t)(nBase + (g + 0) * 16 + r) * Dd + q * 8;
    const ushort* bS1 = Bm + (size_t)(nBase + (g + 1) * 16 + r) * Dd + q * 8;

    auto stage = [&](int it) {
        const int buf = it & 1, dk = it * BK;
        gload16(aS0 + dk, &As[buf][(g + 0) * 512]);
        gload16(aS1 + dk, &As[buf][(g + 1) * 512]);
        gload16(bS0 + dk, &Bs[buf][(g + 0) * 512]);
        gload16(bS1 + dk, &Bs[buf][(g + 1) * 512]);
    };

    stage(0);
    for (int it = 0; it < KITERS; ++it) {
        __syncthreads();  // stage(it) landed; prev iter's LDS reads done
        if (it + 1 < KITERS) stage(it + 1);  // prefetch into other buffer
        const int buf = it & 1;
        bffrag af[2], bfr[8];
#pragma unroll
        for (int mi = 0; mi < 2; ++mi)
            af[mi] = *(const bffrag*)&As[buf][((2 * w + mi) * 64 + lane) * 8];
#pragma unroll
        for (int ni = 0; ni < 8; ++ni)
            bfr[ni] = *(const bffrag*)&Bs[buf][(ni * 64 + lane) * 8];
#pragma unroll
        for (int mi = 0; mi < 2; ++mi)
#pragma unroll
            for (int ni = 0; ni < 8; ++ni)
                acc[mi][ni] = __builtin_amdgcn_mfma_f32_16x16x32_bf16(
                    af[mi], bfr[ni], acc[mi][ni], 0, 0, 0);
    }

    // epilogue. C/D layout: col = lane&15 (+ni*16), row = (lane>>4)*4 + reg.
    // score = max(esq - 2*cross, 0) >= 0 -> raw float bits are the sort key.
    uint32_t colc[8];
    float e8[8];
#pragma unroll
    for (int ni = 0; ni < 8; ++ni) {
        colc[ni] = (uint32_t)(nBase + ni * 16 + (lane & 15));
        e8[ni] = esq[colc[ni]];
    }
#pragma unroll
    for (int mi = 0; mi < 2; ++mi) {
#pragma unroll
        for (int reg = 0; reg < 4; ++reg) {
            u64 p[8];
#pragma unroll
            for (int ni = 0; ni < 8; ++ni) {
                float s = fmaxf(fmaf(-2.f, acc[mi][ni][reg], e8[ni]), 0.f);
                p[ni] = ((u64)__float_as_uint(s) << 32) | colc[ni];
            }
            mm2(p[0], p[1]); mm2(p[2], p[3]); mm2(p[4], p[5]); mm2(p[6], p[7]);
            merge2(p[0], p[1], p[2], p[3]);
            merge2(p[4], p[5], p[6], p[7]);
            merge2(p[0], p[1], p[4], p[5]);
            u64 t1 = p[0], t2 = p[1];
#pragma unroll
            for (int d = 1; d < 16; d <<= 1) {
                u64 o1 = __shfl_xor(t1, d, 64);
                u64 o2 = __shfl_xor(t2, d, 64);
                merge2(t1, t2, o1, o2);
            }
            if ((lane & 15) == 0) {
                const int t = mBase + w * 32 + mi * 16 + (lane >> 4) * 4 + reg;
                cand[(size_t)t * NCAND + nG * 2 + 0] = t1;
                cand[(size_t)t * NCAND + nG * 2 + 1] = t2;
            }
        }
    }
}

// ---------- fused select(top-4 of 128) + exact fp32 rescore ----------
// grid 4096 (one block per token), 256 threads.
__global__ __launch_bounds__(256) void selres_kernel(const u64* __restrict__ cand,
                                                     const float* __restrict__ xT,
                                                     const float* __restrict__ cb,
                                                     const float* __restrict__ esq,
                                                     int* __restrict__ fidx) {
    __shared__ int cs[4];
    __shared__ float red[4][4];
    const int t = blockIdx.x, tid = threadIdx.x;
    if (tid < 64) {  // wave 0: global top-4 of the 128 candidates
        u64 v[2];
#pragma unroll
        for (int j = 0; j < 2; ++j) v[j] = cand[(size_t)t * NCAND + tid * 2 + j];
#pragma unroll
        for (int rd = 0; rd < 4; ++rd) {
            u64 m = v[0] < v[1] ? v[0] : v[1];
#pragma unroll
            for (int d = 32; d; d >>= 1) {
                u64 o = __shfl_xor(m, d, 64);
                m = m < o ? m : o;
            }
            if (tid == 0) cs[rd] = (int)(uint32_t)m;
#pragma unroll
            for (int j = 0; j < 2; ++j)
                if (v[j] == m) v[j] = ~0ULL;  // packed keys unique per token
        }
    }
    __syncthreads();
    int c[4];
#pragma unroll
    for (int j = 0; j < 4; ++j) c[j] = cs[j];
    float4 xv = *(const float4*)&xT[(size_t)t * Dd + tid * 4];
    float part[4];
#pragma unroll
    for (int cc = 0; cc < 4; ++cc) {
        float4 wv = *(const float4*)&cb[(size_t)c[cc] * Dd + tid * 4];
        part[cc] = xv.x * wv.x + xv.y * wv.y + xv.z * wv.z + xv.w * wv.w;
    }
#pragma unroll
    for (int cc = 0; cc < 4; ++cc)
#pragma unroll
        for (int off = 32; off; off >>= 1) part[cc] += __shfl_down(part[cc], off, 64);
    if ((tid & 63) == 0)
#pragma unroll
        for (int cc = 0; cc < 4; ++cc) red[tid >> 6][cc] = part[cc];
    __syncthreads();
    if (tid == 0) {
        float bs = 1e30f;
        int bi = 0x7FFFFFFF;
#pragma unroll
        for (int cc = 0; cc < 4; ++cc) {
            float cross = red[0][cc] + red[1][cc] + red[2][cc] + red[3][cc];
            float s = fmaf(-2.f, cross, esq[c[cc]]);
            if (s < bs || (s == bs && c[cc] < bi)) { bs = s; bi = c[cc]; }
        }
        fidx[t] = bi;
    }
}

// ---------- gather values -> out ----------
__global__ __launch_bounds__(256) void gather_kernel(const int* __restrict__ fidx,
                                                     const float* __restrict__ values,
                                                     float* __restrict__ out) {
    const int n = threadIdx.x, b = blockIdx.x, dc = blockIdx.y;
    const int row = fidx[b * Nn + n];
    const float* src = values + (size_t)row * Dd + dc * 64;
    float* dst = out + (size_t)b * Dd * Nn + (size_t)dc * 64 * Nn + n;
#pragma unroll
    for (int j = 0; j < 64; j += 4) {
        float4 v = *(const float4*)(src + j);
        dst[(j + 0) * Nn] = v.x;
        dst[(j + 1) * Nn] = v.y;
        dst[(j + 2) * Nn] = v.z;
        dst[(j + 3) * Nn] = v.w;
    }
}

extern "C" void kernel_launch(void* const* d_in, const int* in_sizes, int n_in,
                              void* d_out, int out_size, void* d_ws, size_t ws_size,
                              hipStream_t stream) {
    const float* x = (const float*)d_in[0];
    const float* cb = (const float*)d_in[1];
    const float* vals = (const float*)d_in[2];
    float* out = (float*)d_out;

    // ws layout (~28.1 MB). xT (16 MB) aliases Abf+Bbf (dead after dist).
    char* p = (char*)d_ws;
    ushort* Abf = (ushort*)p;                 p += (size_t)Mm * Dd * 2;        // 8 MB
    ushort* Bbf = (ushort*)p;                 p += (size_t)Kk * Dd * 2;        // 16 MB
    float* esq = (float*)p;                   p += (size_t)Kk * 4;             // 32 KB
    u64* cand = (u64*)p;                      p += (size_t)Mm * NCAND * 8;     // 4 MB
    int* fidx = (int*)p;                                                       // 16 KB
    float* xT = (float*)d_ws;  // [4096][1024] fp32, reuses first 16 MB

    prep_kernel<<<Kk + 512, 256, 0, stream>>>(x, cb, Abf, Bbf, esq);
    mfma_dist_kernel<<<dim3(64, 32), 256, 0, stream>>>(Abf, Bbf, esq, cand);
    transx_kernel<<<dim3(Bb, 32), 256, 0, stream>>>(x, xT);
    selres_kernel<<<Mm, 256, 0, stream>>>(cand, xT, cb, esq, fidx);
    gather_kernel<<<dim3(Bb, Dd / 64), 256, 0, stream>>>(fidx, vals, out);
}

// Round 7
// 193.743 us; speedup vs baseline: 2.0242x; 1.4562x over previous
//
#include <hip/hip_runtime.h>
#include <cstdint>

// VectorQuantizer: x[16,1024,16,16] f32, codebook[1,8192,1024], values[1,8192,1024]
// Round 7: i8 screening GEMM via mfma_i32_16x16x64_i8 (K=64 -> 16 stages instead
// of 32, half the barrier round-trips and staged bytes of the bf16 path), verified
// 16x16-family C/D epilogue (r3 code), exact fp32 rescore of global top-4.
// Quantization: s=24, clamp +-127; integer dot is exact; score = esq - 2*dot/s^2.

constexpr int Dd = 1024;   // feature dim (GEMM K)
constexpr int Nn = 256;    // tokens per batch
constexpr int Bb = 16;     // batch
constexpr int Kk = 8192;   // codes (GEMM N)
constexpr int Mm = 4096;   // tokens (GEMM M)
constexpr int BM = 128, BN = 128, BK = 64;
constexpr int STAGES = Dd / BK;     // 16
constexpr int NCHUNK = Kk / 64;     // 128 chunks of 64 codes
constexpr int NCAND = NCHUNK * 2;   // 256 candidates per token
constexpr float QS = 24.0f;         // quant scale
constexpr float SC2 = 2.0f / (QS * QS);

typedef __attribute__((ext_vector_type(4))) int vi4;       // 16 i8 = 4 VGPRs
typedef unsigned long long u64;
typedef unsigned char uchar;

__device__ __forceinline__ void gload16(const void* g, void* l) {
    // async global->LDS; lds dest = wave-uniform base + lane*16 (verified r2-r5)
    __builtin_amdgcn_global_load_lds((const __attribute__((address_space(1))) uint32_t*)g,
                                     (__attribute__((address_space(3))) uint32_t*)l, 16, 0, 0);
}

__device__ __forceinline__ void mm2(u64& a, u64& b) {  // sort pair ascending
    u64 lo = a < b ? a : b;
    u64 hi = a < b ? b : a;
    a = lo; b = hi;
}
// merge sorted pairs: (a1,a2) <- top-2 of {a1,a2,b1,b2}
__device__ __forceinline__ void merge2(u64& a1, u64& a2, u64 b1, u64 b2) {
    u64 t1 = a1 < b1 ? a1 : b1;
    u64 hi = a1 < b1 ? b1 : a1;
    u64 l2 = a2 < b2 ? a2 : b2;
    a2 = hi < l2 ? hi : l2;
    a1 = t1;
}

__device__ __forceinline__ int q8(float v) {  // round-to-nearest, clamp [-127,127]
    int qi = (int)rintf(v * QS);
    qi = qi > 127 ? 127 : (qi < -127 ? -127 : qi);
    return qi & 0xFF;
}
__device__ __forceinline__ int pk4i(float a, float b, float c, float d) {
    return q8(a) | (q8(b) << 8) | (q8(c) << 16) | (q8(d) << 24);
}

// Fragment-order packed layout (A and B identical; verified-symmetric for the
// 16x16 family): P[(g*16 + kb)*64 + lane]*16B, g = row>>4, kb = k>>6,
// lane = (row&15) | (q<<4), q = (k>>4)&3, byte j = k&15.

// ---------- prep ----------
// grid: [0,512) cb->Bpk + esq; [512,1024) x->Apk; [1024,1536) x->xT (bigws only)
__global__ __launch_bounds__(256) void prep_kernel(const float* __restrict__ x,
                                                   const float* __restrict__ cb,
                                                   uchar* __restrict__ Apk,
                                                   uchar* __restrict__ Bpk,
                                                   float* __restrict__ esq,
                                                   float* __restrict__ xT) {
    const int tid = threadIdx.x;
    if (blockIdx.x < 512) {  // codebook: 16 codes/block; thread=(rl 4b hi, seg 4b lo)
        const int rl = tid >> 4, seg = tid & 15;   // seg == kb
        const int code = blockIdx.x * 16 + rl;
        const float* src = cb + (size_t)code * Dd + seg * 64;
        float v[64];
        float ss = 0.f;
#pragma unroll
        for (int j = 0; j < 64; j += 4) {
            float4 f = *(const float4*)&src[j];
            v[j] = f.x; v[j + 1] = f.y; v[j + 2] = f.z; v[j + 3] = f.w;
            ss += f.x * f.x + f.y * f.y + f.z * f.z + f.w * f.w;
        }
#pragma unroll
        for (int off = 8; off; off >>= 1) ss += __shfl_down(ss, off, 16);
        if (seg == 0) esq[code] = ss;
        const int g = code >> 4, rlane = code & 15;
#pragma unroll
        for (int q = 0; q < 4; ++q) {
            int o[4];
#pragma unroll
            for (int w4 = 0; w4 < 4; ++w4) {
                const int j = q * 16 + w4 * 4;
                o[w4] = pk4i(v[j], v[j + 1], v[j + 2], v[j + 3]);
            }
            *(uint4*)&Bpk[((size_t)(g * 16 + seg) * 64 + (rlane | (q << 4))) * 16] =
                *(const uint4*)o;
        }
    } else if (blockIdx.x < 1024) {  // x -> Apk: block=(b, d-chunk of 32), thread=n
        const int bb = blockIdx.x - 512;
        const int b = bb >> 5, d0 = (bb & 31) * 32, n = tid;
        const int t = b * 256 + n;
        const float* xb = x + (size_t)b * Dd * Nn + n;
        const int g = t >> 4, rlane = t & 15, kb = d0 >> 6, qbase = (d0 & 32) >> 4;
        float v[32];
#pragma unroll
        for (int jj = 0; jj < 32; ++jj) v[jj] = xb[(size_t)(d0 + jj) * Nn];
#pragma unroll
        for (int h = 0; h < 2; ++h) {
            int o[4];
#pragma unroll
            for (int w4 = 0; w4 < 4; ++w4) {
                const int j = h * 16 + w4 * 4;
                o[w4] = pk4i(v[j], v[j + 1], v[j + 2], v[j + 3]);
            }
            *(uint4*)&Apk[((size_t)(g * 16 + kb) * 64 + (rlane | ((qbase + h) << 4))) * 16] =
                *(const uint4*)o;
        }
    } else {  // x -> xT fp32 (only when xT doesn't alias Apk/Bpk)
        const int bb = blockIdx.x - 1024;
        const int b = bb >> 5, d0 = (bb & 31) * 32, n = tid;
        const float* xb = x + (size_t)b * Dd * Nn + n;
        float* row = xT + (size_t)(b * Nn + n) * Dd + d0;
#pragma unroll
        for (int jj = 0; jj < 8; ++jj) {
            float4 v;
            v.x = xb[(size_t)(d0 + jj * 4 + 0) * Nn];
            v.y = xb[(size_t)(d0 + jj * 4 + 1) * Nn];
            v.z = xb[(size_t)(d0 + jj * 4 + 2) * Nn];
            v.w = xb[(size_t)(d0 + jj * 4 + 3) * Nn];
            *(float4*)&row[jj * 4] = v;
        }
    }
}

// ---------- x -> xT fp32 (fallback path, AFTER dist; aliases Apk/Bpk region) ----------
__global__ __launch_bounds__(256) void transx_kernel(const float* __restrict__ x,
                                                     float* __restrict__ xT) {
    const int n = threadIdx.x, b = blockIdx.x, d0 = blockIdx.y * 32;
    const float* xb = x + (size_t)b * Dd * Nn + n;
    float* row = xT + (size_t)(b * Nn + n) * Dd + d0;
#pragma unroll
    for (int jj = 0; jj < 8; ++jj) {
        float4 v;
        v.x = xb[(size_t)(d0 + jj * 4 + 0) * Nn];
        v.y = xb[(size_t)(d0 + jj * 4 + 1) * Nn];
        v.z = xb[(size_t)(d0 + jj * 4 + 2) * Nn];
        v.w = xb[(size_t)(d0 + jj * 4 + 3) * Nn];
        *(float4*)&row[jj * 4] = v;
    }
}

// ---------- i8 MFMA distance, ping-pong, 16 stages ----------
// grid (64, 32); 4 waves 2x2 (wm,wn); wave = 64x64 = 4x4 tiles of 16x16x64.
__global__ __launch_bounds__(256) void mfma_dist_kernel(const uchar* __restrict__ Apk,
                                                        const uchar* __restrict__ Bpk,
                                                        const float* __restrict__ esq,
                                                        u64* __restrict__ cand) {
    __shared__ uchar As[2][8192];  // 8 groups x 1KB per buffer
    __shared__ uchar Bs[2][8192];

    const int tid = threadIdx.x, lane = tid & 63, w = tid >> 6;
    const int wm = w >> 1, wn = w & 1;
    const int mBase = blockIdx.y * BM, nBase = blockIdx.x * BN;
    const int gA = blockIdx.y * 8, gB = blockIdx.x * 8;  // global 16-row group bases

    vi4 acc[4][4];
#pragma unroll
    for (int i = 0; i < 4; ++i)
#pragma unroll
        for (int j = 0; j < 4; ++j) acc[i][j] = (vi4)0;

    // wave w stages groups 2w, 2w+1 of A and of B for each stage's kb
    const int g = 2 * w;
    auto stage = [&](int s) {
        const int buf = s & 1;
        gload16(Apk + ((size_t)((gA + g + 0) * 16 + s) * 64 + lane) * 16,
                &As[buf][(g + 0) * 1024]);
        gload16(Apk + ((size_t)((gA + g + 1) * 16 + s) * 64 + lane) * 16,
                &As[buf][(g + 1) * 1024]);
        gload16(Bpk + ((size_t)((gB + g + 0) * 16 + s) * 64 + lane) * 16,
                &Bs[buf][(g + 0) * 1024]);
        gload16(Bpk + ((size_t)((gB + g + 1) * 16 + s) * 64 + lane) * 16,
                &Bs[buf][(g + 1) * 1024]);
    };

    stage(0);
    for (int s = 0; s < STAGES; ++s) {
        __syncthreads();                     // stage(s) visible; prev buf reads done
        if (s + 1 < STAGES) stage(s + 1);    // prefetch other buffer
        const int buf = s & 1;
        vi4 af[4], bf[4];
#pragma unroll
        for (int mi = 0; mi < 4; ++mi)
            af[mi] = *(const vi4*)&As[buf][((wm * 4 + mi) * 64 + lane) * 16];
#pragma unroll
        for (int ni = 0; ni < 4; ++ni)
            bf[ni] = *(const vi4*)&Bs[buf][((wn * 4 + ni) * 64 + lane) * 16];
#pragma unroll
        for (int mi = 0; mi < 4; ++mi)
#pragma unroll
            for (int ni = 0; ni < 4; ++ni)
                acc[mi][ni] = __builtin_amdgcn_mfma_i32_16x16x64_i8(
                    af[mi], bf[ni], acc[mi][ni], 0, 0, 0);
    }

    // Epilogue (verified r3 structure). C/D: col = lane&15 (+ni*16),
    // row = (lane>>4)*4 + reg. score = max(esq - (2/s^2)*dot, 0) -> raw-bit keys.
    const int chunk = blockIdx.x * 2 + wn;
    uint32_t colc[4];
    float e4[4];
#pragma unroll
    for (int ni = 0; ni < 4; ++ni) {
        colc[ni] = (uint32_t)(nBase + wn * 64 + ni * 16 + (lane & 15));
        e4[ni] = esq[colc[ni]];
    }
#pragma unroll
    for (int mi = 0; mi < 4; ++mi) {
#pragma unroll
        for (int reg = 0; reg < 4; ++reg) {
            u64 p[4];
#pragma unroll
            for (int ni = 0; ni < 4; ++ni) {
                float s = fmaxf(fmaf(-SC2, (float)acc[mi][ni][reg], e4[ni]), 0.f);
                p[ni] = ((u64)__float_as_uint(s) << 32) | colc[ni];
            }
            mm2(p[0], p[1]); mm2(p[2], p[3]);
            merge2(p[0], p[1], p[2], p[3]);
            u64 t1 = p[0], t2 = p[1];
#pragma unroll
            for (int d = 1; d < 16; d <<= 1) {
                u64 o1 = __shfl_xor(t1, d, 64);
                u64 o2 = __shfl_xor(t2, d, 64);
                merge2(t1, t2, o1, o2);
            }
            if ((lane & 15) == 0) {
                const int t = mBase + wm * 64 + mi * 16 + (lane >> 4) * 4 + reg;
                cand[(size_t)t * NCAND + chunk * 2 + 0] = t1;
                cand[(size_t)t * NCAND + chunk * 2 + 1] = t2;
            }
        }
    }
}

// ---------- fused select(top-4 of 256) + exact fp32 rescore ----------
__global__ __launch_bounds__(256) void selres_kernel(const u64* __restrict__ cand,
                                                     const float* __restrict__ xT,
                                                     const float* __restrict__ cb,
                                                     const float* __restrict__ esq,
                                                     int* __restrict__ fidx) {
    __shared__ u64 wtop[4][4];
    __shared__ int cs[4];
    __shared__ float red[4][4];
    const int t = blockIdx.x, tid = threadIdx.x, lane = tid & 63, w = tid >> 6;
    u64 v = cand[(size_t)t * NCAND + tid];
#pragma unroll
    for (int rd = 0; rd < 4; ++rd) {  // per-wave top-4
        u64 m = v;
#pragma unroll
        for (int d = 32; d; d >>= 1) {
            u64 o = __shfl_xor(m, d, 64);
            m = m < o ? m : o;
        }
        if (lane == 0) wtop[w][rd] = m;
        if (v == m) v = ~0ULL;  // packed keys unique per token
    }
    __syncthreads();
    if (tid == 0) {  // merge 16 -> global top-4
        u64 a[16];
#pragma unroll
        for (int i = 0; i < 16; ++i) a[i] = wtop[i >> 2][i & 3];
#pragma unroll
        for (int rd = 0; rd < 4; ++rd) {
            int bi = 0;
            u64 m = a[0];
#pragma unroll
            for (int i = 1; i < 16; ++i)
                if (a[i] < m) { m = a[i]; bi = i; }
            cs[rd] = (int)(uint32_t)m;
            a[bi] = ~0ULL;
        }
    }
    __syncthreads();
    int c[4];
#pragma unroll
    for (int j = 0; j < 4; ++j) c[j] = cs[j];
    float4 xv = *(const float4*)&xT[(size_t)t * Dd + tid * 4];
    float part[4];
#pragma unroll
    for (int cc = 0; cc < 4; ++cc) {
        float4 wv = *(const float4*)&cb[(size_t)c[cc] * Dd + tid * 4];
        part[cc] = xv.x * wv.x + xv.y * wv.y + xv.z * wv.z + xv.w * wv.w;
    }
#pragma unroll
    for (int cc = 0; cc < 4; ++cc)
#pragma unroll
        for (int off = 32; off; off >>= 1) part[cc] += __shfl_down(part[cc], off, 64);
    if ((tid & 63) == 0)
#pragma unroll
        for (int cc = 0; cc < 4; ++cc) red[tid >> 6][cc] = part[cc];
    __syncthreads();
    if (tid == 0) {
        float bs = 1e30f;
        int bi = 0x7FFFFFFF;
#pragma unroll
        for (int cc = 0; cc < 4; ++cc) {
            float cross = red[0][cc] + red[1][cc] + red[2][cc] + red[3][cc];
            float s = fmaf(-2.f, cross, esq[c[cc]]);
            if (s < bs || (s == bs && c[cc] < bi)) { bs = s; bi = c[cc]; }
        }
        fidx[t] = bi;
    }
}

// ---------- gather values -> out ----------
__global__ __launch_bounds__(256) void gather_kernel(const int* __restrict__ fidx,
                                                     const float* __restrict__ values,
                                                     float* __restrict__ out) {
    const int n = threadIdx.x, b = blockIdx.x, dc = blockIdx.y;
    const int row = fidx[b * Nn + n];
    const float* src = values + (size_t)row * Dd + dc * 64;
    float* dst = out + (size_t)b * Dd * Nn + (size_t)dc * 64 * Nn + n;
#pragma unroll
    for (int j = 0; j < 64; j += 4) {
        float4 v = *(const float4*)(src + j);
        dst[(j + 0) * Nn] = v.x;
        dst[(j + 1) * Nn] = v.y;
        dst[(j + 2) * Nn] = v.z;
        dst[(j + 3) * Nn] = v.w;
    }
}

extern "C" void kernel_launch(void* const* d_in, const int* in_sizes, int n_in,
                              void* d_out, int out_size, void* d_ws, size_t ws_size,
                              hipStream_t stream) {
    const float* x = (const float*)d_in[0];
    const float* cb = (const float*)d_in[1];
    const float* vals = (const float*)d_in[2];
    float* out = (float*)d_out;

    // ws: [Apk 4M][Bpk 8M][pad->16M][esq 32K][cand 8M][fidx 16K] = 24.28 MB.
    // bigws: xT gets its own 16 MB after that (40.3 MB) and prep fills it;
    // else xT aliases the first 16 MB and is filled post-dist by transx.
    char* p = (char*)d_ws;
    uchar* Apk = (uchar*)p;
    uchar* Bpk = (uchar*)(p + ((size_t)4 << 20));
    float* esq = (float*)(p + ((size_t)16 << 20));
    u64* cand = (u64*)(p + ((size_t)16 << 20) + Kk * 4);
    int* fidx = (int*)(p + ((size_t)16 << 20) + Kk * 4 + (size_t)Mm * NCAND * 8);
    const size_t base = ((size_t)16 << 20) + Kk * 4 + (size_t)Mm * NCAND * 8 + Mm * 4;
    const bool bigws = ws_size >= base + ((size_t)16 << 20);
    float* xT = bigws ? (float*)(p + base) : (float*)d_ws;

    prep_kernel<<<bigws ? 1536 : 1024, 256, 0, stream>>>(x, cb, Apk, Bpk, esq, xT);
    mfma_dist_kernel<<<dim3(64, 32), 256, 0, stream>>>(Apk, Bpk, esq, cand);
    if (!bigws) transx_kernel<<<dim3(Bb, 32), 256, 0, stream>>>(x, xT);
    selres_kernel<<<Mm, 256, 0, stream>>>(cand, xT, cb, esq, fidx);
    gather_kernel<<<dim3(Bb, Dd / 64), 256, 0, stream>>>(fidx, vals, out);
}